// Round 7
// baseline (536.290 us; speedup 1.0000x reference)
//
#include <hip/hip_runtime.h>
#include <hip/hip_bf16.h>

// ---------------------------------------------------------------------------
// Attention_81449759801699 on MI355X (gfx950)
// R7: attention rewritten on 32x32x16 MFMA, barrier-free / LDS-free.
// Per wave: 32 q rows x 128 dv. Swapped QK^T -> P lane-local per q-col;
// in-register softmax (m=0, log2e folded); P->A-frag repack via 8 shfl_xor;
// PV 32x32. Bias C-init stays vectorized (u32x2). GELU with hw rcp.
// dv-partner waves duplicate QK (no inter-wave communication at all).
// GEMMs: m97 128x128 structure; proj runs full-batch when ws allows.
// ---------------------------------------------------------------------------

typedef unsigned short u16;
typedef unsigned int u32;
typedef float  f32x4  __attribute__((ext_vector_type(4)));
typedef float  f32x16 __attribute__((ext_vector_type(16)));
typedef float  fl4    __attribute__((ext_vector_type(4)));
typedef short  short8 __attribute__((ext_vector_type(8)));
typedef u32    u32x4  __attribute__((ext_vector_type(4)));
typedef u32    u32x2  __attribute__((ext_vector_type(2)));

#define EPSF 1e-5f
#define NH 8
#define NTP 416                        // 400 text tokens padded to 416 (13*32)
#define LOG2E 1.4426950408889634f
#define QSCALE (0.125f * LOG2E)

static __device__ __forceinline__ u16 f2bf(float f){
  u32 u = __builtin_bit_cast(u32, f);
  u += 0x7FFFu + ((u >> 16) & 1u);     // RNE (finite inputs only)
  return (u16)(u >> 16);
}
static __device__ __forceinline__ float u2f(u32 u){
  return __builtin_bit_cast(float, u);
}
static __device__ __forceinline__ u32 pk2bf(float lo, float hi){
  float2 f; f.x = lo; f.y = hi;
  __hip_bfloat162 b = __float22bfloat162_rn(f);
  u32 l = (u32)__bfloat16_as_ushort(b.x);
  u32 h = (u32)__bfloat16_as_ushort(b.y);
  return l | (h << 16);
}
static __device__ __forceinline__ f32x4 mfma16(short8 a, short8 b, f32x4 c){
  return __builtin_amdgcn_mfma_f32_16x16x32_bf16(a, b, c, 0, 0, 0);
}
static __device__ __forceinline__ f32x16 mfma32(short8 a, short8 b, f32x16 c){
  return __builtin_amdgcn_mfma_f32_32x32x16_bf16(a, b, c, 0, 0, 0);
}
static __device__ __forceinline__ void gld16(const void* g, void* l){
  __builtin_amdgcn_global_load_lds(
      (const __attribute__((address_space(1))) u32*)g,
      (__attribute__((address_space(3))) u32*)l, 16, 0, 0);
}

// ---------------------------------------------------------------------------
// Weight convert: wT[c][r] = bf16(w[r][c] * gamma[c]*rsqrt(var[c]+eps))
// ---------------------------------------------------------------------------
__global__ __launch_bounds__(256) void wconv_kernel(
    const float* __restrict__ w, const float* __restrict__ gamma,
    const float* __restrict__ var, u16* __restrict__ wT, int R, int C)
{
  __shared__ u16 tile[64*65];
  const int tx = blockIdx.x, ty = blockIdx.y, tid = threadIdx.x;
  #pragma unroll
  for (int i = 0; i < 16; ++i){
    int lin = tid + i*256;
    int rr = lin >> 6, cc = lin & 63;
    int c = tx*64 + cc;
    float s = gamma[c] * rsqrtf(var[c] + EPSF);
    tile[rr*65 + cc] = f2bf(w[(size_t)(ty*64 + rr)*C + c] * s);
  }
  __syncthreads();
  #pragma unroll
  for (int i = 0; i < 16; ++i){
    int lin = tid + i*256;
    int cc = lin >> 6, rr = lin & 63;
    wT[(size_t)(tx*64 + cc)*R + ty*64 + rr] = tile[rr*65 + cc];
  }
}

// text -> bf16, padded to 512 rows (rows >=400 zero)
__global__ __launch_bounds__(256) void textconv_kernel(
    const float* __restrict__ text, u16* __restrict__ tbf)
{
  int idx = blockIdx.x*256 + threadIdx.x;   // 512*512
  int r = idx >> 9, c = idx & 511;
  float v = (r < 400) ? text[r*512 + c] : 0.f;
  tbf[idx] = f2bf(v);
}

// bias table: btab[h][n][t] bf16, pre-multiplied by log2e; t>=400 -> -1e30
__global__ __launch_bounds__(256) void bias_kernel(
    const float* __restrict__ ab, u16* __restrict__ btab)
{
  int idx = blockIdx.x*256 + threadIdx.x;   // 8*1024*416
  int t = idx % 416;
  int n = (idx / 416) & 1023;
  int h = idx / (416*1024);
  float v;
  if (t >= 400) v = -1e30f;
  else {
    int i = n >> 5, j = n & 31;
    int a = t / 100, bb = t % 100;
    v = ab[h*10000 + abs(i - a)*100 + abs(j - bb)] * LOG2E;
  }
  btab[idx] = f2bf(v);
}

// ---------------------------------------------------------------------------
// 128x128 tile GEMM (m97 structure). BT is [N][K] bf16 (BN scale folded).
// MODE 0: A=x fp32 (reg-stage cvt) -> q_ws[b][h][n][64] bf16, *QSCALE folded
// MODE 1: A=text_bf -> K_ws[h][t][64], V_ws[h][dv][t] bf16 (t<416 guard)
// MODE 2: A=a_ws bf16 -> d_out fp32 (+BN shift), rows offset row_base
// ---------------------------------------------------------------------------
template<int MODE>
__global__ __launch_bounds__(256) void gemm_kernel(
    const void* __restrict__ Ap, const u16* __restrict__ BT,
    const float* __restrict__ g1, const float* __restrict__ b1,
    const float* __restrict__ m1, const float* __restrict__ v1,
    void* __restrict__ o0, void* __restrict__ o1, int K, int row_base)
{
  __shared__ u16 lds[8192];                 // A [0,4096), B [4096,8192)
  const int tid = threadIdx.x;
  const int cb = blockIdx.x, rb = blockIdx.y;
  const int lane = tid & 63, wid = tid >> 6;
  const int lg = lane >> 4, lc = lane & 15;
  const int wr = wid >> 1, wc = wid & 1;
  const int row0 = rb*128, col0 = cb*128;
  f32x4 acc[4][4] = {};
  const int nkb = K >> 5;

  for (int kb = 0; kb < nkb; ++kb){
    if (MODE == 0){
      const float* A = (const float*)Ap;
      #pragma unroll
      for (int it = 0; it < 4; ++it){
        int lin = tid + it*256;
        int row = lin >> 3, c4 = lin & 7;
        const fl4 v = *(const fl4*)(A + (size_t)(row0 + row)*K + kb*32 + c4*4);
        u32x2 p;
        p[0] = (u32)f2bf(v[0]) | ((u32)f2bf(v[1]) << 16);
        p[1] = (u32)f2bf(v[2]) | ((u32)f2bf(v[3]) << 16);
        *(u32x2*)&lds[row*32 + c4*4] = p;
      }
    } else {
      const u16* A = (const u16*)Ap;
      #pragma unroll
      for (int it = 0; it < 2; ++it){
        int lin = tid + it*256;
        int row = lin >> 2, seg = lin & 3;
        gld16(A + (size_t)(row0 + row)*K + kb*32 + seg*8, &lds[lin*8]);
      }
    }
    #pragma unroll
    for (int it = 0; it < 2; ++it){
      int lin = tid + it*256;
      int col = lin >> 2, seg = lin & 3;
      gld16(BT + (size_t)(col0 + col)*K + kb*32 + seg*8, &lds[4096 + lin*8]);
    }
    __syncthreads();
    short8 af[4], bfr[4];
    #pragma unroll
    for (int rt = 0; rt < 4; ++rt)
      af[rt] = *(const short8*)&lds[(wr*64 + rt*16 + lc)*32 + lg*8];
    #pragma unroll
    for (int ct = 0; ct < 4; ++ct)
      bfr[ct] = *(const short8*)&lds[4096 + (wc*64 + ct*16 + lc)*32 + lg*8];
    #pragma unroll
    for (int rt = 0; rt < 4; ++rt)
      #pragma unroll
      for (int ct = 0; ct < 4; ++ct)
        acc[rt][ct] = mfma16(af[rt], bfr[ct], acc[rt][ct]);
    __syncthreads();
  }

  if (MODE == 0){
    u16* qws = (u16*)o0;
    #pragma unroll
    for (int ct = 0; ct < 4; ++ct){
      int c = col0 + wc*64 + ct*16 + lc;
      float sc = g1[c] * rsqrtf(v1[c] + EPSF);
      float sh = (b1[c] - m1[c]*sc) * QSCALE;   // 0.125*log2e fold
      int h = c >> 6, dk = c & 63;
      #pragma unroll
      for (int rt = 0; rt < 4; ++rt)
        #pragma unroll
        for (int r = 0; r < 4; ++r){
          int mr = row0 + wr*64 + rt*16 + lg*4 + r;
          int b = mr >> 10, n = mr & 1023;
          qws[(size_t)((b*NH + h)*1024 + n)*64 + dk] =
              f2bf(acc[rt][ct][r]*QSCALE + sh);
        }
    }
  } else if (MODE == 1){
    u16* Kw = (u16*)o0; u16* Vw = (u16*)o1;
    #pragma unroll
    for (int ct = 0; ct < 4; ++ct){
      int c = col0 + wc*64 + ct*16 + lc;
      float sc = g1[c] * rsqrtf(v1[c] + EPSF);
      float sh = b1[c] - m1[c]*sc;
      int h = c / 320, sub = c % 320;
      #pragma unroll
      for (int rt = 0; rt < 4; ++rt)
        #pragma unroll
        for (int r = 0; r < 4; ++r){
          int t = row0 + wr*64 + rt*16 + lg*4 + r;
          if (t < NTP){
            u16 val = f2bf(acc[rt][ct][r] + sh);
            if (sub < 64) Kw[(size_t)(h*NTP + t)*64 + sub] = val;
            else          Vw[(size_t)(h*256 + (sub - 64))*NTP + t] = val;
          }
        }
    }
  } else {
    float* outp = (float*)o0;
    #pragma unroll
    for (int ct = 0; ct < 4; ++ct){
      int c = col0 + wc*64 + ct*16 + lc;
      float sc = g1[c] * rsqrtf(v1[c] + EPSF);
      float sh = b1[c] - m1[c]*sc;
      #pragma unroll
      for (int rt = 0; rt < 4; ++rt)
        #pragma unroll
        for (int r = 0; r < 4; ++r){
          int mr = row_base + row0 + wr*64 + rt*16 + lg*4 + r;
          outp[(size_t)mr*512 + c] = acc[rt][ct][r] + sh;
        }
    }
  }
}

// ---------------------------------------------------------------------------
// Attention, 32x32x16 MFMA, barrier-free / LDS-free.
// Block 256 thr = 4 independent waves: wave = (qg = wid>>1, dvh = wid&1).
// Wave: 32 q rows (n0q..+31) x 128 dv (dvh*128..+127), all 416 t.
// QK swapped: D[t][q] (col=lane&31=q, row=(reg&3)+8(reg>>2)+4hi=t).
// P repack to PV A-frags: pairs packed bf16, 8 shfl_xor(32)/tile.
// ---------------------------------------------------------------------------
__global__ __launch_bounds__(256, 2) void attn_kernel(
    const u16* __restrict__ qws, const u16* __restrict__ Kw,
    const u16* __restrict__ Vw, const u16* __restrict__ btab,
    u16* __restrict__ aws, int b_base)
{
  const int tid = threadIdx.x;
  const int lane = tid & 63, wid = tid >> 6;
  const int l31 = lane & 31, hi = lane >> 5;
  const int qg = wid >> 1, dvh = wid & 1;
  const int h = blockIdx.y, bz = blockIdx.z;
  const int b = b_base + bz;
  const int n0q = blockIdx.x*64 + qg*32;
  const int dvb = dvh*128;

  // Q B-frags: col q=l31, k = m*16 + hi*8 + j  (QSCALE folded at q-proj)
  const u16* qp = qws + ((size_t)((b*NH + h)*1024 + n0q + l31))*64 + hi*8;
  short8 qf0 = *(const short8*)(qp);
  short8 qf1 = *(const short8*)(qp + 16);
  short8 qf2 = *(const short8*)(qp + 32);
  short8 qf3 = *(const short8*)(qp + 48);

  // K A-frags: row t = c*32 + l31, k = m*16 + hi*8 + j
  const u16* kp = Kw + ((size_t)h*NTP + l31)*64 + hi*8;
  // bias: q row = n0q + l31; t = c*32 + s*8 + hi*4 + {0..3}  (x log2e)
  const u16* bp = btab + ((size_t)h*1024 + n0q + l31)*416 + hi*4;
  // V B-frags: col dv = dvb + d*32 + l31, k t = c*32 + tau*16 + hi*8 + j
  const u16* vp = Vw + ((size_t)h*256 + dvb + l31)*NTP + hi*8;

  f32x16 acc[4] = {};
  float lpart = 0.f;

  #pragma unroll
  for (int c = 0; c < 13; ++c){
    // ---- V loads issued early (consumed ~100 VALU ops later)
    short8 vf[2][4];
    #pragma unroll
    for (int d = 0; d < 4; ++d){
      vf[0][d] = *(const short8*)(vp + (size_t)d*32*NTP + c*32);
      vf[1][d] = *(const short8*)(vp + (size_t)d*32*NTP + c*32 + 16);
    }
    // ---- K frags for this 32-t tile
    short8 kf0 = *(const short8*)(kp + c*2048);
    short8 kf1 = *(const short8*)(kp + c*2048 + 16);
    short8 kf2 = *(const short8*)(kp + c*2048 + 32);
    short8 kf3 = *(const short8*)(kp + c*2048 + 48);
    // ---- bias C-init: sc[4s+r] = bias[q][c*32 + 8s + 4hi + r]
    f32x16 sc;
    #pragma unroll
    for (int s = 0; s < 4; ++s){
      u32x2 bw = *(const u32x2*)(bp + c*32 + s*8);
      sc[4*s+0] = u2f(bw[0] << 16);
      sc[4*s+1] = u2f(bw[0] & 0xffff0000u);
      sc[4*s+2] = u2f(bw[1] << 16);
      sc[4*s+3] = u2f(bw[1] & 0xffff0000u);
    }
    // ---- QK^T (swapped): D[t][q] += K.Q over dk=64
    sc = mfma32(kf0, qf0, sc);
    sc = mfma32(kf1, qf1, sc);
    sc = mfma32(kf2, qf2, sc);
    sc = mfma32(kf3, qf3, sc);
    // ---- softmax numerators (m=0), pack to bf16 pairs along t
    float p[16];
    #pragma unroll
    for (int i = 0; i < 16; ++i){ p[i] = __builtin_exp2f(sc[i]); }
    #pragma unroll
    for (int i = 0; i < 16; ++i){ lpart += p[i]; }
    u32 pk[8], xk[8];
    #pragma unroll
    for (int s = 0; s < 4; ++s){
      pk[2*s]   = pk2bf(p[4*s+0], p[4*s+1]);   // t pair (8s+4hi, +1)
      pk[2*s+1] = pk2bf(p[4*s+2], p[4*s+3]);   // t pair (8s+4hi+2, +3)
    }
    #pragma unroll
    for (int i = 0; i < 8; ++i) xk[i] = (u32)__shfl_xor((int)pk[i], 32);
    // ---- assemble PV A-frags: A0 = t 0..15, A1 = t 16..31 (k = hi*8 + j)
    u32x4 a0u, a1u;
    a0u[0] = hi ? xk[2] : pk[0];  a0u[1] = hi ? xk[3] : pk[1];
    a0u[2] = hi ? pk[2] : xk[0];  a0u[3] = hi ? pk[3] : xk[1];
    a1u[0] = hi ? xk[6] : pk[4];  a1u[1] = hi ? xk[7] : pk[5];
    a1u[2] = hi ? pk[6] : xk[4];  a1u[3] = hi ? pk[7] : xk[5];
    short8 A0 = __builtin_bit_cast(short8, a0u);
    short8 A1 = __builtin_bit_cast(short8, a1u);
    // ---- PV: D[q][dv] += P.V
    #pragma unroll
    for (int d = 0; d < 4; ++d){
      acc[d] = mfma32(A0, vf[0][d], acc[d]);
      acc[d] = mfma32(A1, vf[1][d], acc[d]);
    }
  }

  // ---- row sums: partner half holds the other 16 t per q
  lpart += __shfl_xor(lpart, 32);
  float linv = __builtin_amdgcn_rcpf(lpart);    // lane l: 1/sum for q = l&31
  float li[16];
  #pragma unroll
  for (int i = 0; i < 16; ++i){
    int qrow = (i & 3) + 8*(i >> 2) + 4*hi;
    li[i] = __shfl(linv, qrow);
  }

  // ---- epilogue: /l, exact GELU (A&S erf, hw rcp), write aws bf16
  #pragma unroll
  for (int d = 0; d < 4; ++d){
    #pragma unroll
    for (int i = 0; i < 16; ++i){
      float x = acc[d][i] * li[i];
      float uu = x * 0.70710678f;
      float au = fabsf(uu);
      float t = __builtin_amdgcn_rcpf(__builtin_fmaf(0.3275911f, au, 1.0f));
      float poly = t*(0.254829592f + t*(-0.284496736f + t*(1.421413741f +
                   t*(-1.453152027f + t*1.061405429f))));
      float e = __builtin_exp2f(-uu*uu*LOG2E);
      float erfv = 1.0f - poly*e;
      erfv = (uu < 0.f) ? -erfv : erfv;
      float g = 0.5f * x * (1.0f + erfv);
      int qrow = (i & 3) + 8*(i >> 2) + 4*hi;
      aws[((size_t)(bz*1024 + n0q + qrow))*2048 + h*256 + dvb + d*32 + l31] =
          f2bf(g);
    }
  }
}

// ---------------------------------------------------------------------------
extern "C" void kernel_launch(void* const* d_in, const int* in_sizes, int n_in,
                              void* d_out, int out_size, void* d_ws, size_t ws_size,
                              hipStream_t stream)
{
  (void)in_sizes; (void)n_in; (void)out_size;
  const float* x    = (const float*)d_in[0];
  const float* text = (const float*)d_in[1];
  const float* q_w  = (const float*)d_in[2];
  const float* q_g  = (const float*)d_in[3];
  const float* q_b  = (const float*)d_in[4];
  const float* q_m  = (const float*)d_in[5];
  const float* q_v  = (const float*)d_in[6];
  const float* kv_w = (const float*)d_in[7];
  const float* kv_g = (const float*)d_in[8];
  const float* kv_b = (const float*)d_in[9];
  const float* kv_m = (const float*)d_in[10];
  const float* kv_v = (const float*)d_in[11];
  const float* p_w  = (const float*)d_in[12];
  const float* p_g  = (const float*)d_in[13];
  const float* p_b  = (const float*)d_in[14];
  const float* p_m  = (const float*)d_in[15];
  const float* p_v  = (const float*)d_in[16];
  const float* ab   = (const float*)d_in[17];
  float* out = (float*)d_out;

  char* ws = (char*)d_ws;
  u16* qwT   = (u16*)(ws + 0);            //  512x512   [N][K]
  u16* kvwT  = (u16*)(ws + 524288);       // 2560x512   [N][K]
  u16* pwT   = (u16*)(ws + 3145728);      //  512x2048  [N][K]
  u16* textb = (u16*)(ws + 5242880);      //  512x512
  u16* btab  = (u16*)(ws + 5767168);      //  8x1024x416 (x log2e)
  u16* Kw    = (u16*)(ws + 12582912);     //  8x416x64
  u16* Vw    = (u16*)(ws + 13008896);     //  8x256x416 (transposed)
  u16* qws   = (u16*)(ws + 14712832);     //  32x8x1024x64
  u16* aws   = (u16*)(ws + 48267264);     //  32768x2048 (full) or 8192x2048

  const bool full = ws_size >= (size_t)182484992ull;

  wconv_kernel<<<dim3(8, 8),  256, 0, stream>>>(q_w,  q_g,  q_v,  qwT,  512,  512);
  wconv_kernel<<<dim3(40, 8), 256, 0, stream>>>(kv_w, kv_g, kv_v, kvwT, 512,  2560);
  wconv_kernel<<<dim3(8, 32), 256, 0, stream>>>(p_w,  p_g,  p_v,  pwT,  2048, 512);
  textconv_kernel<<<1024, 256, 0, stream>>>(text, textb);
  bias_kernel<<<13312, 256, 0, stream>>>(ab, btab);

  // kv-proj: M=512(pad) N=2560 K=512
  gemm_kernel<1><<<dim3(20, 4), 256, 0, stream>>>(
      textb, kvwT, kv_g, kv_b, kv_m, kv_v, Kw, Vw, 512, 0);
  // q-proj: M=32768 N=512 K=512
  gemm_kernel<0><<<dim3(4, 256), 256, 0, stream>>>(
      x, qwT, q_g, q_b, q_m, q_v, qws, nullptr, 512, 0);

  if (full){
    attn_kernel<<<dim3(16, 8, 32), 256, 0, stream>>>(qws, Kw, Vw, btab, aws, 0);
    // proj: M=32768 N=512 K=2048
    gemm_kernel<2><<<dim3(4, 256), 256, 0, stream>>>(
        aws, pwT, p_g, p_b, p_m, p_v, out, nullptr, 2048, 0);
  } else {
    for (int q = 0; q < 4; ++q){
      attn_kernel<<<dim3(16, 8, 8), 256, 0, stream>>>(qws, Kw, Vw, btab, aws, q*8);
      gemm_kernel<2><<<dim3(4, 64), 256, 0, stream>>>(
          aws, pwT, p_g, p_b, p_m, p_v, out, nullptr, 2048, q*8192);
    }
  }
}

// Round 8
// 410.258 us; speedup vs baseline: 1.3072x; 1.3072x over previous
//
#include <hip/hip_runtime.h>
#include <hip/hip_bf16.h>

// ---------------------------------------------------------------------------
// Attention_81449759801699 on MI355X (gfx950)
// R8 = R6 attention (16x16 swapped QK^T, reg-pipelined K/bias prefetch,
// P double-buffered in LDS, 1 barrier/chunk) with ONE change: XCD-aware
// flat-grid decode so each XCD owns one head (h = L&7) and same-(qt,h)
// bz-blocks run consecutively -> K/V/btab slices stay L2-resident.
// GEMMs: m97 128x128 structure; proj runs full-batch when ws allows.
// ---------------------------------------------------------------------------

typedef unsigned short u16;
typedef unsigned int u32;
typedef float  f32x4  __attribute__((ext_vector_type(4)));
typedef float  fl4    __attribute__((ext_vector_type(4)));
typedef short  short8 __attribute__((ext_vector_type(8)));
typedef u32    u32x4  __attribute__((ext_vector_type(4)));
typedef u32    u32x2  __attribute__((ext_vector_type(2)));

#define EPSF 1e-5f
#define NH 8
#define NTP 416                        // 400 text tokens padded to 416 (13*32)
#define LOG2E 1.4426950408889634f
#define QSCALE (0.125f * LOG2E)

static __device__ __forceinline__ u16 f2bf(float f){
  u32 u = __builtin_bit_cast(u32, f);
  u += 0x7FFFu + ((u >> 16) & 1u);     // RNE (finite inputs only)
  return (u16)(u >> 16);
}
static __device__ __forceinline__ float u2f(u32 u){
  return __builtin_bit_cast(float, u);
}
static __device__ __forceinline__ u32 pk2bf(float lo, float hi){
  float2 f; f.x = lo; f.y = hi;
  __hip_bfloat162 b = __float22bfloat162_rn(f);
  u32 l = (u32)__bfloat16_as_ushort(b.x);
  u32 h = (u32)__bfloat16_as_ushort(b.y);
  return l | (h << 16);
}
static __device__ __forceinline__ f32x4 mfma16(short8 a, short8 b, f32x4 c){
  return __builtin_amdgcn_mfma_f32_16x16x32_bf16(a, b, c, 0, 0, 0);
}
static __device__ __forceinline__ void gld16(const void* g, void* l){
  __builtin_amdgcn_global_load_lds(
      (const __attribute__((address_space(1))) u32*)g,
      (__attribute__((address_space(3))) u32*)l, 16, 0, 0);
}

// ---------------------------------------------------------------------------
// Weight convert: wT[c][r] = bf16(w[r][c] * gamma[c]*rsqrt(var[c]+eps))
// ---------------------------------------------------------------------------
__global__ __launch_bounds__(256) void wconv_kernel(
    const float* __restrict__ w, const float* __restrict__ gamma,
    const float* __restrict__ var, u16* __restrict__ wT, int R, int C)
{
  __shared__ u16 tile[64*65];
  const int tx = blockIdx.x, ty = blockIdx.y, tid = threadIdx.x;
  #pragma unroll
  for (int i = 0; i < 16; ++i){
    int lin = tid + i*256;
    int rr = lin >> 6, cc = lin & 63;
    int c = tx*64 + cc;
    float s = gamma[c] * rsqrtf(var[c] + EPSF);
    tile[rr*65 + cc] = f2bf(w[(size_t)(ty*64 + rr)*C + c] * s);
  }
  __syncthreads();
  #pragma unroll
  for (int i = 0; i < 16; ++i){
    int lin = tid + i*256;
    int cc = lin >> 6, rr = lin & 63;
    wT[(size_t)(tx*64 + cc)*R + ty*64 + rr] = tile[rr*65 + cc];
  }
}

// text -> bf16, padded to 512 rows (rows >=400 zero)
__global__ __launch_bounds__(256) void textconv_kernel(
    const float* __restrict__ text, u16* __restrict__ tbf)
{
  int idx = blockIdx.x*256 + threadIdx.x;   // 512*512
  int r = idx >> 9, c = idx & 511;
  float v = (r < 400) ? text[r*512 + c] : 0.f;
  tbf[idx] = f2bf(v);
}

// bias table: btab[h][n][t] bf16, pre-multiplied by log2e; t>=400 -> -1e30
__global__ __launch_bounds__(256) void bias_kernel(
    const float* __restrict__ ab, u16* __restrict__ btab)
{
  int idx = blockIdx.x*256 + threadIdx.x;   // 8*1024*416
  int t = idx % 416;
  int n = (idx / 416) & 1023;
  int h = idx / (416*1024);
  float v;
  if (t >= 400) v = -1e30f;
  else {
    int i = n >> 5, j = n & 31;
    int a = t / 100, bb = t % 100;
    v = ab[h*10000 + abs(i - a)*100 + abs(j - bb)] * LOG2E;
  }
  btab[idx] = f2bf(v);
}

// ---------------------------------------------------------------------------
// 128x128 tile GEMM (m97 structure). BT is [N][K] bf16 (BN scale folded).
// MODE 0: A=x fp32 (reg-stage cvt) -> q_ws[b][h][n][64] bf16, *QSCALE folded
// MODE 1: A=text_bf -> K_ws[h][t][64], V_ws[h][dv][t] bf16 (t<416 guard)
// MODE 2: A=a_ws bf16 -> d_out fp32 (+BN shift), rows offset row_base
// ---------------------------------------------------------------------------
template<int MODE>
__global__ __launch_bounds__(256) void gemm_kernel(
    const void* __restrict__ Ap, const u16* __restrict__ BT,
    const float* __restrict__ g1, const float* __restrict__ b1,
    const float* __restrict__ m1, const float* __restrict__ v1,
    void* __restrict__ o0, void* __restrict__ o1, int K, int row_base)
{
  __shared__ u16 lds[8192];                 // A [0,4096), B [4096,8192)
  const int tid = threadIdx.x;
  const int cb = blockIdx.x, rb = blockIdx.y;
  const int lane = tid & 63, wid = tid >> 6;
  const int lg = lane >> 4, lc = lane & 15;
  const int wr = wid >> 1, wc = wid & 1;
  const int row0 = rb*128, col0 = cb*128;
  f32x4 acc[4][4] = {};
  const int nkb = K >> 5;

  for (int kb = 0; kb < nkb; ++kb){
    if (MODE == 0){
      const float* A = (const float*)Ap;
      #pragma unroll
      for (int it = 0; it < 4; ++it){
        int lin = tid + it*256;
        int row = lin >> 3, c4 = lin & 7;
        const fl4 v = *(const fl4*)(A + (size_t)(row0 + row)*K + kb*32 + c4*4);
        u32x2 p;
        p[0] = (u32)f2bf(v[0]) | ((u32)f2bf(v[1]) << 16);
        p[1] = (u32)f2bf(v[2]) | ((u32)f2bf(v[3]) << 16);
        *(u32x2*)&lds[row*32 + c4*4] = p;
      }
    } else {
      const u16* A = (const u16*)Ap;
      #pragma unroll
      for (int it = 0; it < 2; ++it){
        int lin = tid + it*256;
        int row = lin >> 2, seg = lin & 3;
        gld16(A + (size_t)(row0 + row)*K + kb*32 + seg*8, &lds[lin*8]);
      }
    }
    #pragma unroll
    for (int it = 0; it < 2; ++it){
      int lin = tid + it*256;
      int col = lin >> 2, seg = lin & 3;
      gld16(BT + (size_t)(col0 + col)*K + kb*32 + seg*8, &lds[4096 + lin*8]);
    }
    __syncthreads();
    short8 af[4], bfr[4];
    #pragma unroll
    for (int rt = 0; rt < 4; ++rt)
      af[rt] = *(const short8*)&lds[(wr*64 + rt*16 + lc)*32 + lg*8];
    #pragma unroll
    for (int ct = 0; ct < 4; ++ct)
      bfr[ct] = *(const short8*)&lds[4096 + (wc*64 + ct*16 + lc)*32 + lg*8];
    #pragma unroll
    for (int rt = 0; rt < 4; ++rt)
      #pragma unroll
      for (int ct = 0; ct < 4; ++ct)
        acc[rt][ct] = mfma16(af[rt], bfr[ct], acc[rt][ct]);
    __syncthreads();
  }

  if (MODE == 0){
    u16* qws = (u16*)o0;
    #pragma unroll
    for (int ct = 0; ct < 4; ++ct){
      int c = col0 + wc*64 + ct*16 + lc;
      float sc = g1[c] * rsqrtf(v1[c] + EPSF);
      float sh = (b1[c] - m1[c]*sc) * QSCALE;   // 0.125*log2e fold
      int h = c >> 6, dk = c & 63;
      #pragma unroll
      for (int rt = 0; rt < 4; ++rt)
        #pragma unroll
        for (int r = 0; r < 4; ++r){
          int mr = row0 + wr*64 + rt*16 + lg*4 + r;
          int b = mr >> 10, n = mr & 1023;
          qws[(size_t)((b*NH + h)*1024 + n)*64 + dk] =
              f2bf(acc[rt][ct][r]*QSCALE + sh);
        }
    }
  } else if (MODE == 1){
    u16* Kw = (u16*)o0; u16* Vw = (u16*)o1;
    #pragma unroll
    for (int ct = 0; ct < 4; ++ct){
      int c = col0 + wc*64 + ct*16 + lc;
      float sc = g1[c] * rsqrtf(v1[c] + EPSF);
      float sh = b1[c] - m1[c]*sc;
      int h = c / 320, sub = c % 320;
      #pragma unroll
      for (int rt = 0; rt < 4; ++rt)
        #pragma unroll
        for (int r = 0; r < 4; ++r){
          int t = row0 + wr*64 + rt*16 + lg*4 + r;
          if (t < NTP){
            u16 val = f2bf(acc[rt][ct][r] + sh);
            if (sub < 64) Kw[(size_t)(h*NTP + t)*64 + sub] = val;
            else          Vw[(size_t)(h*256 + (sub - 64))*NTP + t] = val;
          }
        }
    }
  } else {
    float* outp = (float*)o0;
    #pragma unroll
    for (int ct = 0; ct < 4; ++ct){
      int c = col0 + wc*64 + ct*16 + lc;
      float sc = g1[c] * rsqrtf(v1[c] + EPSF);
      float sh = b1[c] - m1[c]*sc;
      #pragma unroll
      for (int rt = 0; rt < 4; ++rt)
        #pragma unroll
        for (int r = 0; r < 4; ++r){
          int mr = row_base + row0 + wr*64 + rt*16 + lg*4 + r;
          outp[(size_t)mr*512 + c] = acc[rt][ct][r] + sh;
        }
    }
  }
}

// ---------------------------------------------------------------------------
// Flash attention, swapped QK^T, direct K/V/bias loads, register-pipelined.
// R8: flat grid, XCD-aware decode. With round-robin L->XCD (L&7):
//   xcd = L&7 owns head h = xcd; within an XCD the 32 same-(qt,h) bz blocks
//   are slot-consecutive -> K/V/btab head slices stay L2-resident.
// Block = 64 q x (h, b); 4 waves. Wave w: QK+softmax for q [16w,16w+16);
// PV for all 64 q x dv [64w,64w+64). Chunk = 32 t, 13 chunks, full unroll.
// P double-buffered in LDS (2 x 5120 B), 1 barrier per chunk.
// ---------------------------------------------------------------------------
__global__ __launch_bounds__(256, 3) void attn_kernel(
    const u16* __restrict__ qws, const u16* __restrict__ Kw,
    const u16* __restrict__ Vw, const u16* __restrict__ btab,
    u16* __restrict__ aws, int b_base, int bzbits)
{
  __shared__ char Pb[2][64*80];     // P bf16 [64 q][32 t], row stride 80 B
  __shared__ float lsum[64];

  const int tid = threadIdx.x;
  const int lane = tid & 63, wid = tid >> 6;
  const int lg = lane >> 4, lc = lane & 15;

  // XCD-aware decode: L = slot*8 + xcd (HW round-robins xcd = L&7)
  const int L = blockIdx.x;
  const int xcd = L & 7;
  const int slot = L >> 3;
  const int bz = slot & ((1 << bzbits) - 1);
  const int qt = slot >> bzbits;            // 0..15
  const int h = xcd;                        // one head per XCD
  const int b = b_base + bz, n0 = qt*64;

  // Q B-frags (col=q=lc within wave's 16 rows), QSCALE folded at q-proj
  const u16* qp = qws + ((size_t)((b*NH + h)*1024 + n0 + wid*16 + lc))*64 + lg*8;
  const short8 qf0 = *(const short8*)qp;
  const short8 qf1 = *(const short8*)(qp + 32);

  // K A-frag rows: t = c*32 + tt*16 + lc, k-elems lg*8 (+32)
  const u16* kbase = Kw + ((size_t)h*NTP + lc)*64 + lg*8;
  // V B-frag cols: dv = wid*64 + ct*16 + lc, k (t) = c*32 + lg*8
  const u16* vp0 = Vw + ((size_t)h*256 + wid*64      + lc)*NTP + lg*8;
  const u16* vp1 = vp0 + (size_t)16*NTP;
  const u16* vp2 = vp0 + (size_t)32*NTP;
  const u16* vp3 = vp0 + (size_t)48*NTP;
  // bias row for this lane's q (pre-scaled by log2e)
  const u16* bt = btab + ((size_t)h*1024 + n0 + wid*16 + lc)*416;

  float lpart = 0.f;
  f32x4 acc[4][4] = {};
  char* pwr = &Pb[0][0] + (wid*16 + lc)*80 + lg*8;   // + buf*5120 + tt*32

  // prefetch slots (static indices via full unroll)
  short8 kfs[2][4];                 // [slot][tt*2 + khalf]
  u32x2  bws[2][2];                 // [slot][tt]

  // prologue: issue K/bias for chunk 0 into slot 0
  kfs[0][0] = *(const short8*)(kbase);
  kfs[0][1] = *(const short8*)(kbase + 32);
  kfs[0][2] = *(const short8*)(kbase + 1024);
  kfs[0][3] = *(const short8*)(kbase + 1024 + 32);
  bws[0][0] = *(const u32x2*)(bt + lg*4);
  bws[0][1] = *(const u32x2*)(bt + 16 + lg*4);

  #pragma unroll
  for (int c = 0; c < 13; ++c){
    const int s = c & 1, ns = (c + 1) & 1;
    // ---- issue V(c) loads (consumed after barrier)
    short8 vf0 = *(const short8*)(vp0 + c*32);
    short8 vf1 = *(const short8*)(vp1 + c*32);
    short8 vf2 = *(const short8*)(vp2 + c*32);
    short8 vf3 = *(const short8*)(vp3 + c*32);
    // ---- QK(c) with prefetched K/bias; write P into Pb[s]
    #pragma unroll
    for (int tt = 0; tt < 2; ++tt){
      u32x2 bw = bws[s][tt];
      f32x4 sv;
      sv[0] = u2f(bw[0] << 16); sv[1] = u2f(bw[0] & 0xffff0000u);
      sv[2] = u2f(bw[1] << 16); sv[3] = u2f(bw[1] & 0xffff0000u);
      sv = mfma16(kfs[s][tt*2 + 0], qf0, sv);
      sv = mfma16(kfs[s][tt*2 + 1], qf1, sv);
      float p0 = __builtin_exp2f(sv[0]);
      float p1 = __builtin_exp2f(sv[1]);
      float p2 = __builtin_exp2f(sv[2]);
      float p3 = __builtin_exp2f(sv[3]);
      lpart += (p0 + p1) + (p2 + p3);
      u32x2 pw;
      pw[0] = pk2bf(p0, p1);
      pw[1] = pk2bf(p2, p3);
      *(u32x2*)(pwr + s*5120 + tt*32) = pw;
    }
    // ---- issue K/bias(c+1) into slot ns (consumed next iteration)
    if (c < 12){
      const u16* kc = kbase + (size_t)(c + 1)*2048;
      kfs[ns][0] = *(const short8*)(kc);
      kfs[ns][1] = *(const short8*)(kc + 32);
      kfs[ns][2] = *(const short8*)(kc + 1024);
      kfs[ns][3] = *(const short8*)(kc + 1024 + 32);
      bws[ns][0] = *(const u32x2*)(bt + (c + 1)*32 + lg*4);
      bws[ns][1] = *(const u32x2*)(bt + (c + 1)*32 + 16 + lg*4);
    }
    __syncthreads();                                  // Pb[s] ready for all
    // ---- PV(c): all 64 q x this wave's 64 dv
    const char* pb = &Pb[s][0];
    short8 pa[4];
    #pragma unroll
    for (int rt = 0; rt < 4; ++rt)
      pa[rt] = *(const short8*)(pb + (rt*16 + lc)*80 + lg*16);
    #pragma unroll
    for (int rt = 0; rt < 4; ++rt){
      acc[rt][0] = mfma16(pa[rt], vf0, acc[rt][0]);
      acc[rt][1] = mfma16(pa[rt], vf1, acc[rt][1]);
      acc[rt][2] = mfma16(pa[rt], vf2, acc[rt][2]);
      acc[rt][3] = mfma16(pa[rt], vf3, acc[rt][3]);
    }
  }

  // ---- row sums -> LDS
  lpart += __shfl_xor(lpart, 16);
  lpart += __shfl_xor(lpart, 32);
  if (lane < 16) lsum[wid*16 + lane] = lpart;
  __syncthreads();

  // ---- epilogue: /l, exact GELU (A&S erf), write aws bf16
  #pragma unroll
  for (int rt = 0; rt < 4; ++rt){
    #pragma unroll
    for (int r = 0; r < 4; ++r){
      const int qrow = rt*16 + lg*4 + r;
      const float linv = 1.0f / lsum[qrow];
      const size_t obase = ((size_t)(bz*1024 + n0 + qrow))*2048 + h*256;
      #pragma unroll
      for (int ct = 0; ct < 4; ++ct){
        float x = acc[rt][ct][r] * linv;
        float u = x * 0.70710678f;
        float au = fabsf(u);
        float t = 1.0f / (1.0f + 0.3275911f*au);
        float poly = t*(0.254829592f + t*(-0.284496736f + t*(1.421413741f +
                     t*(-1.453152027f + t*1.061405429f))));
        float erfv = 1.0f - poly*__expf(-u*u);
        erfv = (u < 0.f) ? -erfv : erfv;
        float g = 0.5f * x * (1.0f + erfv);
        aws[obase + wid*64 + ct*16 + lc] = f2bf(g);
      }
    }
  }
}

// ---------------------------------------------------------------------------
extern "C" void kernel_launch(void* const* d_in, const int* in_sizes, int n_in,
                              void* d_out, int out_size, void* d_ws, size_t ws_size,
                              hipStream_t stream)
{
  (void)in_sizes; (void)n_in; (void)out_size;
  const float* x    = (const float*)d_in[0];
  const float* text = (const float*)d_in[1];
  const float* q_w  = (const float*)d_in[2];
  const float* q_g  = (const float*)d_in[3];
  const float* q_b  = (const float*)d_in[4];
  const float* q_m  = (const float*)d_in[5];
  const float* q_v  = (const float*)d_in[6];
  const float* kv_w = (const float*)d_in[7];
  const float* kv_g = (const float*)d_in[8];
  const float* kv_b = (const float*)d_in[9];
  const float* kv_m = (const float*)d_in[10];
  const float* kv_v = (const float*)d_in[11];
  const float* p_w  = (const float*)d_in[12];
  const float* p_g  = (const float*)d_in[13];
  const float* p_b  = (const float*)d_in[14];
  const float* p_m  = (const float*)d_in[15];
  const float* p_v  = (const float*)d_in[16];
  const float* ab   = (const float*)d_in[17];
  float* out = (float*)d_out;

  char* ws = (char*)d_ws;
  u16* qwT   = (u16*)(ws + 0);            //  512x512   [N][K]
  u16* kvwT  = (u16*)(ws + 524288);       // 2560x512   [N][K]
  u16* pwT   = (u16*)(ws + 3145728);      //  512x2048  [N][K]
  u16* textb = (u16*)(ws + 5242880);      //  512x512
  u16* btab  = (u16*)(ws + 5767168);      //  8x1024x416 (x log2e)
  u16* Kw    = (u16*)(ws + 12582912);     //  8x416x64
  u16* Vw    = (u16*)(ws + 13008896);     //  8x256x416 (transposed)
  u16* qws   = (u16*)(ws + 14712832);     //  32x8x1024x64
  u16* aws   = (u16*)(ws + 48267264);     //  32768x2048 (full) or 8192x2048

  const bool full = ws_size >= (size_t)182484992ull;

  wconv_kernel<<<dim3(8, 8),  256, 0, stream>>>(q_w,  q_g,  q_v,  qwT,  512,  512);
  wconv_kernel<<<dim3(40, 8), 256, 0, stream>>>(kv_w, kv_g, kv_v, kvwT, 512,  2560);
  wconv_kernel<<<dim3(8, 32), 256, 0, stream>>>(p_w,  p_g,  p_v,  pwT,  2048, 512);
  textconv_kernel<<<1024, 256, 0, stream>>>(text, textb);
  bias_kernel<<<13312, 256, 0, stream>>>(ab, btab);

  // kv-proj: M=512(pad) N=2560 K=512
  gemm_kernel<1><<<dim3(20, 4), 256, 0, stream>>>(
      textb, kvwT, kv_g, kv_b, kv_m, kv_v, Kw, Vw, 512, 0);
  // q-proj: M=32768 N=512 K=512
  gemm_kernel<0><<<dim3(4, 256), 256, 0, stream>>>(
      x, qwT, q_g, q_b, q_m, q_v, qws, nullptr, 512, 0);

  if (full){
    // flat 4096 blocks: xcd=L&7 (head), slot=L>>3: bz=slot&31, qt=slot>>5
    attn_kernel<<<4096, 256, 0, stream>>>(qws, Kw, Vw, btab, aws, 0, 5);
    // proj: M=32768 N=512 K=2048
    gemm_kernel<2><<<dim3(4, 256), 256, 0, stream>>>(
        aws, pwT, p_g, p_b, p_m, p_v, out, nullptr, 2048, 0);
  } else {
    for (int q = 0; q < 4; ++q){
      attn_kernel<<<1024, 256, 0, stream>>>(qws, Kw, Vw, btab, aws, q*8, 3);
      gemm_kernel<2><<<dim3(4, 64), 256, 0, stream>>>(
          aws, pwT, p_g, p_b, p_m, p_v, out, nullptr, 2048, q*8192);
    }
  }
}

// Round 9
// 338.618 us; speedup vs baseline: 1.5838x; 1.2116x over previous
//
#include <hip/hip_runtime.h>
#include <hip/hip_bf16.h>

// ---------------------------------------------------------------------------
// Attention_81449759801699 on MI355X (gfx950)
// R9 = R8 + fragment-tiled K/V/bias layouts (producer-side) so every attn
// global load is fully coalesced (1KB/512B contiguous per wave-instruction,
// was 64 scattered lines for V). Same QK/P/PV structure, XCD decode, K/bias
// reg-prefetch. Epilogue divides -> v_rcp; setprio(1) around PV MFMAs (T5).
// Layouts (u16 units):
//  K:  (h*13+c)*2048 + tt*1024 + kh*512 + lg*128 + lc*8 + j
//  V:  (h*13+c)*8192 + wid*2048 + ct*512 + lg*128 + lc*8 + j
//  B:  ((h*16+qt)*13+c)*2048 + wid*512 + tt*256 + lg*64 + lc*4 + e
// GEMMs: m97 128x128 structure; proj runs full-batch when ws allows.
// ---------------------------------------------------------------------------

typedef unsigned short u16;
typedef unsigned int u32;
typedef float  f32x4  __attribute__((ext_vector_type(4)));
typedef float  fl4    __attribute__((ext_vector_type(4)));
typedef short  short8 __attribute__((ext_vector_type(8)));
typedef u32    u32x4  __attribute__((ext_vector_type(4)));
typedef u32    u32x2  __attribute__((ext_vector_type(2)));

#define EPSF 1e-5f
#define NH 8
#define NTP 416                        // 400 text tokens padded to 416 (13*32)
#define LOG2E 1.4426950408889634f
#define QSCALE (0.125f * LOG2E)

static __device__ __forceinline__ u16 f2bf(float f){
  u32 u = __builtin_bit_cast(u32, f);
  u += 0x7FFFu + ((u >> 16) & 1u);     // RNE (finite inputs only)
  return (u16)(u >> 16);
}
static __device__ __forceinline__ float u2f(u32 u){
  return __builtin_bit_cast(float, u);
}
static __device__ __forceinline__ u32 pk2bf(float lo, float hi){
  float2 f; f.x = lo; f.y = hi;
  __hip_bfloat162 b = __float22bfloat162_rn(f);
  u32 l = (u32)__bfloat16_as_ushort(b.x);
  u32 h = (u32)__bfloat16_as_ushort(b.y);
  return l | (h << 16);
}
static __device__ __forceinline__ f32x4 mfma16(short8 a, short8 b, f32x4 c){
  return __builtin_amdgcn_mfma_f32_16x16x32_bf16(a, b, c, 0, 0, 0);
}
static __device__ __forceinline__ void gld16(const void* g, void* l){
  __builtin_amdgcn_global_load_lds(
      (const __attribute__((address_space(1))) u32*)g,
      (__attribute__((address_space(3))) u32*)l, 16, 0, 0);
}

// ---------------------------------------------------------------------------
// Weight convert: wT[c][r] = bf16(w[r][c] * gamma[c]*rsqrt(var[c]+eps))
// ---------------------------------------------------------------------------
__global__ __launch_bounds__(256) void wconv_kernel(
    const float* __restrict__ w, const float* __restrict__ gamma,
    const float* __restrict__ var, u16* __restrict__ wT, int R, int C)
{
  __shared__ u16 tile[64*65];
  const int tx = blockIdx.x, ty = blockIdx.y, tid = threadIdx.x;
  #pragma unroll
  for (int i = 0; i < 16; ++i){
    int lin = tid + i*256;
    int rr = lin >> 6, cc = lin & 63;
    int c = tx*64 + cc;
    float s = gamma[c] * rsqrtf(var[c] + EPSF);
    tile[rr*65 + cc] = f2bf(w[(size_t)(ty*64 + rr)*C + c] * s);
  }
  __syncthreads();
  #pragma unroll
  for (int i = 0; i < 16; ++i){
    int lin = tid + i*256;
    int cc = lin >> 6, rr = lin & 63;
    wT[(size_t)(tx*64 + cc)*R + ty*64 + rr] = tile[rr*65 + cc];
  }
}

// text -> bf16, padded to 512 rows (rows >=400 zero)
__global__ __launch_bounds__(256) void textconv_kernel(
    const float* __restrict__ text, u16* __restrict__ tbf)
{
  int idx = blockIdx.x*256 + threadIdx.x;   // 512*512
  int r = idx >> 9, c = idx & 511;
  float v = (r < 400) ? text[r*512 + c] : 0.f;
  tbf[idx] = f2bf(v);
}

// bias table, fragment-tiled (x log2e); t>=400 -> -1e30
__global__ __launch_bounds__(256) void bias_kernel(
    const float* __restrict__ ab, u16* __restrict__ btab)
{
  int idx = blockIdx.x*256 + threadIdx.x;   // 8*1024*416
  int t = idx % 416;
  int n = (idx / 416) & 1023;
  int h = idx / (416*1024);
  float v;
  if (t >= 400) v = -1e30f;
  else {
    int i = n >> 5, j = n & 31;
    int a = t / 100, bb = t % 100;
    v = ab[h*10000 + abs(i - a)*100 + abs(j - bb)] * LOG2E;
  }
  size_t o = ((size_t)(h*16 + (n >> 6))*13 + (t >> 5))*2048
           + ((n >> 4) & 3)*512 + ((t >> 4) & 1)*256
           + ((t >> 2) & 3)*64 + (n & 15)*4 + (t & 3);
  btab[o] = f2bf(v);
}

// ---------------------------------------------------------------------------
// 128x128 tile GEMM (m97 structure). BT is [N][K] bf16 (BN scale folded).
// MODE 0: A=x fp32 (reg-stage cvt) -> q_ws[b][h][n][64] bf16, *QSCALE folded
// MODE 1: A=text_bf -> K/V fragment-tiled (t<416 guard)
// MODE 2: A=a_ws bf16 -> d_out fp32 (+BN shift), rows offset row_base
// ---------------------------------------------------------------------------
template<int MODE>
__global__ __launch_bounds__(256) void gemm_kernel(
    const void* __restrict__ Ap, const u16* __restrict__ BT,
    const float* __restrict__ g1, const float* __restrict__ b1,
    const float* __restrict__ m1, const float* __restrict__ v1,
    void* __restrict__ o0, void* __restrict__ o1, int K, int row_base)
{
  __shared__ u16 lds[8192];                 // A [0,4096), B [4096,8192)
  const int tid = threadIdx.x;
  const int cb = blockIdx.x, rb = blockIdx.y;
  const int lane = tid & 63, wid = tid >> 6;
  const int lg = lane >> 4, lc = lane & 15;
  const int wr = wid >> 1, wc = wid & 1;
  const int row0 = rb*128, col0 = cb*128;
  f32x4 acc[4][4] = {};
  const int nkb = K >> 5;

  for (int kb = 0; kb < nkb; ++kb){
    if (MODE == 0){
      const float* A = (const float*)Ap;
      #pragma unroll
      for (int it = 0; it < 4; ++it){
        int lin = tid + it*256;
        int row = lin >> 3, c4 = lin & 7;
        const fl4 v = *(const fl4*)(A + (size_t)(row0 + row)*K + kb*32 + c4*4);
        u32x2 p;
        p[0] = (u32)f2bf(v[0]) | ((u32)f2bf(v[1]) << 16);
        p[1] = (u32)f2bf(v[2]) | ((u32)f2bf(v[3]) << 16);
        *(u32x2*)&lds[row*32 + c4*4] = p;
      }
    } else {
      const u16* A = (const u16*)Ap;
      #pragma unroll
      for (int it = 0; it < 2; ++it){
        int lin = tid + it*256;
        int row = lin >> 2, seg = lin & 3;
        gld16(A + (size_t)(row0 + row)*K + kb*32 + seg*8, &lds[lin*8]);
      }
    }
    #pragma unroll
    for (int it = 0; it < 2; ++it){
      int lin = tid + it*256;
      int col = lin >> 2, seg = lin & 3;
      gld16(BT + (size_t)(col0 + col)*K + kb*32 + seg*8, &lds[4096 + lin*8]);
    }
    __syncthreads();
    short8 af[4], bfr[4];
    #pragma unroll
    for (int rt = 0; rt < 4; ++rt)
      af[rt] = *(const short8*)&lds[(wr*64 + rt*16 + lc)*32 + lg*8];
    #pragma unroll
    for (int ct = 0; ct < 4; ++ct)
      bfr[ct] = *(const short8*)&lds[4096 + (wc*64 + ct*16 + lc)*32 + lg*8];
    #pragma unroll
    for (int rt = 0; rt < 4; ++rt)
      #pragma unroll
      for (int ct = 0; ct < 4; ++ct)
        acc[rt][ct] = mfma16(af[rt], bfr[ct], acc[rt][ct]);
    __syncthreads();
  }

  if (MODE == 0){
    u16* qws = (u16*)o0;
    #pragma unroll
    for (int ct = 0; ct < 4; ++ct){
      int c = col0 + wc*64 + ct*16 + lc;
      float sc = g1[c] * rsqrtf(v1[c] + EPSF);
      float sh = (b1[c] - m1[c]*sc) * QSCALE;   // 0.125*log2e fold
      int h = c >> 6, dk = c & 63;
      #pragma unroll
      for (int rt = 0; rt < 4; ++rt)
        #pragma unroll
        for (int r = 0; r < 4; ++r){
          int mr = row0 + wr*64 + rt*16 + lg*4 + r;
          int b = mr >> 10, n = mr & 1023;
          qws[(size_t)((b*NH + h)*1024 + n)*64 + dk] =
              f2bf(acc[rt][ct][r]*QSCALE + sh);
        }
    }
  } else if (MODE == 1){
    u16* Kw = (u16*)o0; u16* Vw = (u16*)o1;
    #pragma unroll
    for (int ct = 0; ct < 4; ++ct){
      int c = col0 + wc*64 + ct*16 + lc;
      float sc = g1[c] * rsqrtf(v1[c] + EPSF);
      float sh = b1[c] - m1[c]*sc;
      int h = c / 320, sub = c % 320;
      #pragma unroll
      for (int rt = 0; rt < 4; ++rt)
        #pragma unroll
        for (int r = 0; r < 4; ++r){
          int t = row0 + wr*64 + rt*16 + lg*4 + r;
          if (t < NTP){
            u16 val = f2bf(acc[rt][ct][r] + sh);
            if (sub < 64){
              // K fragment-tiled
              size_t o = ((size_t)h*13 + (t >> 5))*2048
                       + ((t >> 4) & 1)*1024 + (sub >> 5)*512
                       + ((sub >> 3) & 3)*128 + (t & 15)*8 + (sub & 7);
              Kw[o] = val;
            } else {
              int dv = sub - 64;
              // V fragment-tiled
              size_t o = ((size_t)h*13 + (t >> 5))*8192
                       + (dv >> 6)*2048 + ((dv >> 4) & 3)*512
                       + ((t >> 3) & 3)*128 + (dv & 15)*8 + (t & 7);
              Vw[o] = val;
            }
          }
        }
    }
  } else {
    float* outp = (float*)o0;
    #pragma unroll
    for (int ct = 0; ct < 4; ++ct){
      int c = col0 + wc*64 + ct*16 + lc;
      float sc = g1[c] * rsqrtf(v1[c] + EPSF);
      float sh = b1[c] - m1[c]*sc;
      #pragma unroll
      for (int rt = 0; rt < 4; ++rt)
        #pragma unroll
        for (int r = 0; r < 4; ++r){
          int mr = row_base + row0 + wr*64 + rt*16 + lg*4 + r;
          outp[(size_t)mr*512 + c] = acc[rt][ct][r] + sh;
        }
    }
  }
}

// ---------------------------------------------------------------------------
// Flash attention, swapped QK^T, fragment-tiled coalesced loads, reg-pipelined
// K/bias prefetch, XCD-aware flat-grid decode (h = L&7, same-(qt,h) blocks
// slot-consecutive -> K/V/btab head slices L2-resident).
// Block = 64 q x (h, b); 4 waves. Chunk = 32 t, 13 chunks, full unroll.
// P double-buffered in LDS (2 x 5120 B), 1 barrier per chunk.
// ---------------------------------------------------------------------------
__global__ __launch_bounds__(256, 3) void attn_kernel(
    const u16* __restrict__ qws, const u16* __restrict__ Kw,
    const u16* __restrict__ Vw, const u16* __restrict__ btab,
    u16* __restrict__ aws, int b_base, int bzbits)
{
  __shared__ char Pb[2][64*80];     // P bf16 [64 q][32 t], row stride 80 B
  __shared__ float lsum[64];

  const int tid = threadIdx.x;
  const int lane = tid & 63, wid = tid >> 6;
  const int lg = lane >> 4, lc = lane & 15;

  // XCD-aware decode: L = slot*8 + xcd (HW round-robins xcd = L&7)
  const int L = blockIdx.x;
  const int slot = L >> 3;
  const int bz = slot & ((1 << bzbits) - 1);
  const int qt = slot >> bzbits;            // 0..15
  const int h = L & 7;                      // one head per XCD
  const int b = b_base + bz, n0 = qt*64;

  // Q B-frags (col=q=lc within wave's 16 rows), QSCALE folded at q-proj
  const u16* qp = qws + ((size_t)((b*NH + h)*1024 + n0 + wid*16 + lc))*64 + lg*8;
  const short8 qf0 = *(const short8*)qp;
  const short8 qf1 = *(const short8*)(qp + 32);

  // fragment-tiled bases (u16 units) — fully coalesced per-wave reads
  const u16* kbase = Kw + (size_t)h*13*2048 + lg*128 + lc*8;
  const u16* vbase = Vw + (size_t)h*13*8192 + wid*2048 + lg*128 + lc*8;
  const u16* btb   = btab + ((size_t)(h*16 + qt)*13)*2048 + wid*512 + lg*64 + lc*4;

  float lpart = 0.f;
  f32x4 acc[4][4] = {};
  char* pwr = &Pb[0][0] + (wid*16 + lc)*80 + lg*8;   // + buf*5120 + tt*32

  // prefetch slots (static indices via full unroll)
  short8 kfs[2][4];                 // [slot][tt*2 + kh]
  u32x2  bws[2][2];                 // [slot][tt]

  // prologue: issue K/bias for chunk 0 into slot 0
  kfs[0][0] = *(const short8*)(kbase);
  kfs[0][1] = *(const short8*)(kbase + 512);
  kfs[0][2] = *(const short8*)(kbase + 1024);
  kfs[0][3] = *(const short8*)(kbase + 1536);
  bws[0][0] = *(const u32x2*)(btb);
  bws[0][1] = *(const u32x2*)(btb + 256);

  #pragma unroll
  for (int c = 0; c < 13; ++c){
    const int s = c & 1, ns = (c + 1) & 1;
    // ---- issue V(c) loads (consumed after barrier)
    const u16* vc = vbase + (size_t)c*8192;
    short8 vf0 = *(const short8*)(vc);
    short8 vf1 = *(const short8*)(vc + 512);
    short8 vf2 = *(const short8*)(vc + 1024);
    short8 vf3 = *(const short8*)(vc + 1536);
    // ---- QK(c) with prefetched K/bias; write P into Pb[s]
    #pragma unroll
    for (int tt = 0; tt < 2; ++tt){
      u32x2 bw = bws[s][tt];
      f32x4 sv;
      sv[0] = u2f(bw[0] << 16); sv[1] = u2f(bw[0] & 0xffff0000u);
      sv[2] = u2f(bw[1] << 16); sv[3] = u2f(bw[1] & 0xffff0000u);
      sv = mfma16(kfs[s][tt*2 + 0], qf0, sv);
      sv = mfma16(kfs[s][tt*2 + 1], qf1, sv);
      float p0 = __builtin_exp2f(sv[0]);
      float p1 = __builtin_exp2f(sv[1]);
      float p2 = __builtin_exp2f(sv[2]);
      float p3 = __builtin_exp2f(sv[3]);
      lpart += (p0 + p1) + (p2 + p3);
      u32x2 pw;
      pw[0] = pk2bf(p0, p1);
      pw[1] = pk2bf(p2, p3);
      *(u32x2*)(pwr + s*5120 + tt*32) = pw;
    }
    // ---- issue K/bias(c+1) into slot ns (consumed next iteration)
    if (c < 12){
      const u16* kc = kbase + (size_t)(c + 1)*2048;
      kfs[ns][0] = *(const short8*)(kc);
      kfs[ns][1] = *(const short8*)(kc + 512);
      kfs[ns][2] = *(const short8*)(kc + 1024);
      kfs[ns][3] = *(const short8*)(kc + 1536);
      const u16* bc = btb + (size_t)(c + 1)*2048;
      bws[ns][0] = *(const u32x2*)(bc);
      bws[ns][1] = *(const u32x2*)(bc + 256);
    }
    __syncthreads();                                  // Pb[s] ready for all
    // ---- PV(c): all 64 q x this wave's 64 dv
    const char* pb = &Pb[s][0];
    short8 pa[4];
    #pragma unroll
    for (int rt = 0; rt < 4; ++rt)
      pa[rt] = *(const short8*)(pb + (rt*16 + lc)*80 + lg*16);
    __builtin_amdgcn_s_setprio(1);
    #pragma unroll
    for (int rt = 0; rt < 4; ++rt){
      acc[rt][0] = mfma16(pa[rt], vf0, acc[rt][0]);
      acc[rt][1] = mfma16(pa[rt], vf1, acc[rt][1]);
      acc[rt][2] = mfma16(pa[rt], vf2, acc[rt][2]);
      acc[rt][3] = mfma16(pa[rt], vf3, acc[rt][3]);
    }
    __builtin_amdgcn_s_setprio(0);
  }

  // ---- row sums -> LDS
  lpart += __shfl_xor(lpart, 16);
  lpart += __shfl_xor(lpart, 32);
  if (lane < 16) lsum[wid*16 + lane] = lpart;
  __syncthreads();

  // ---- epilogue: /l (rcp), exact GELU (A&S erf, rcp), write aws bf16
  #pragma unroll
  for (int rt = 0; rt < 4; ++rt){
    #pragma unroll
    for (int r = 0; r < 4; ++r){
      const int qrow = rt*16 + lg*4 + r;
      const float linv = __builtin_amdgcn_rcpf(lsum[qrow]);
      const size_t obase = ((size_t)(bz*1024 + n0 + qrow))*2048 + h*256;
      #pragma unroll
      for (int ct = 0; ct < 4; ++ct){
        float x = acc[rt][ct][r] * linv;
        float u = x * 0.70710678f;
        float au = fabsf(u);
        float t = __builtin_amdgcn_rcpf(__builtin_fmaf(0.3275911f, au, 1.0f));
        float poly = t*(0.254829592f + t*(-0.284496736f + t*(1.421413741f +
                     t*(-1.453152027f + t*1.061405429f))));
        float erfv = 1.0f - poly*__expf(-u*u);
        erfv = (u < 0.f) ? -erfv : erfv;
        float g = 0.5f * x * (1.0f + erfv);
        aws[obase + wid*64 + ct*16 + lc] = f2bf(g);
      }
    }
  }
}

// ---------------------------------------------------------------------------
extern "C" void kernel_launch(void* const* d_in, const int* in_sizes, int n_in,
                              void* d_out, int out_size, void* d_ws, size_t ws_size,
                              hipStream_t stream)
{
  (void)in_sizes; (void)n_in; (void)out_size;
  const float* x    = (const float*)d_in[0];
  const float* text = (const float*)d_in[1];
  const float* q_w  = (const float*)d_in[2];
  const float* q_g  = (const float*)d_in[3];
  const float* q_b  = (const float*)d_in[4];
  const float* q_m  = (const float*)d_in[5];
  const float* q_v  = (const float*)d_in[6];
  const float* kv_w = (const float*)d_in[7];
  const float* kv_g = (const float*)d_in[8];
  const float* kv_b = (const float*)d_in[9];
  const float* kv_m = (const float*)d_in[10];
  const float* kv_v = (const float*)d_in[11];
  const float* p_w  = (const float*)d_in[12];
  const float* p_g  = (const float*)d_in[13];
  const float* p_b  = (const float*)d_in[14];
  const float* p_m  = (const float*)d_in[15];
  const float* p_v  = (const float*)d_in[16];
  const float* ab   = (const float*)d_in[17];
  float* out = (float*)d_out;

  char* ws = (char*)d_ws;
  u16* qwT   = (u16*)(ws + 0);            //  512x512   [N][K]
  u16* kvwT  = (u16*)(ws + 524288);       // 2560x512   [N][K]
  u16* pwT   = (u16*)(ws + 3145728);      //  512x2048  [N][K]
  u16* textb = (u16*)(ws + 5242880);      //  512x512
  u16* btab  = (u16*)(ws + 5767168);      //  8x16x13x2048 (frag-tiled, x log2e)
  u16* Kw    = (u16*)(ws + 12582912);     //  8x13x2048 (frag-tiled)
  u16* Vw    = (u16*)(ws + 13008896);     //  8x13x8192 (frag-tiled)
  u16* qws   = (u16*)(ws + 14712832);     //  32x8x1024x64
  u16* aws   = (u16*)(ws + 48267264);     //  32768x2048 (full) or 8192x2048

  const bool full = ws_size >= (size_t)182484992ull;

  wconv_kernel<<<dim3(8, 8),  256, 0, stream>>>(q_w,  q_g,  q_v,  qwT,  512,  512);
  wconv_kernel<<<dim3(40, 8), 256, 0, stream>>>(kv_w, kv_g, kv_v, kvwT, 512,  2560);
  wconv_kernel<<<dim3(8, 32), 256, 0, stream>>>(p_w,  p_g,  p_v,  pwT,  2048, 512);
  textconv_kernel<<<1024, 256, 0, stream>>>(text, textb);
  bias_kernel<<<13312, 256, 0, stream>>>(ab, btab);

  // kv-proj: M=512(pad) N=2560 K=512
  gemm_kernel<1><<<dim3(20, 4), 256, 0, stream>>>(
      textb, kvwT, kv_g, kv_b, kv_m, kv_v, Kw, Vw, 512, 0);
  // q-proj: M=32768 N=512 K=512
  gemm_kernel<0><<<dim3(4, 256), 256, 0, stream>>>(
      x, qwT, q_g, q_b, q_m, q_v, qws, nullptr, 512, 0);

  if (full){
    // flat 4096 blocks: h=L&7, slot=L>>3: bz=slot&31, qt=slot>>5
    attn_kernel<<<4096, 256, 0, stream>>>(qws, Kw, Vw, btab, aws, 0, 5);
    // proj: M=32768 N=512 K=2048
    gemm_kernel<2><<<dim3(4, 256), 256, 0, stream>>>(
        aws, pwT, p_g, p_b, p_m, p_v, out, nullptr, 2048, 0);
  } else {
    for (int q = 0; q < 4; ++q){
      attn_kernel<<<1024, 256, 0, stream>>>(qws, Kw, Vw, btab, aws, q*8, 3);
      gemm_kernel<2><<<dim3(4, 64), 256, 0, stream>>>(
          aws, pwT, p_g, p_b, p_m, p_v, out, nullptr, 2048, q*8192);
    }
  }
}

// Round 10
// 323.542 us; speedup vs baseline: 1.6576x; 1.0466x over previous
//
#include <hip/hip_runtime.h>
#include <hip/hip_bf16.h>

// ---------------------------------------------------------------------------
// Attention_81449759801699 on MI355X (gfx950)
// R10 = R9 + XCD-chunked flat-grid decode for q-proj and proj GEMMs:
// xcd = L&7 owns contiguous rb band; cb iterates fastest within a slot ->
// same-rb blocks temporally adjacent on one XCD -> A-panel fetched once/L2.
// (Mechanism validated in R8/R9 on attention: FETCH 83->21 MB.)
// Attention: R9 fragment-tiled kernel, unchanged.
// ---------------------------------------------------------------------------

typedef unsigned short u16;
typedef unsigned int u32;
typedef float  f32x4  __attribute__((ext_vector_type(4)));
typedef float  fl4    __attribute__((ext_vector_type(4)));
typedef short  short8 __attribute__((ext_vector_type(8)));
typedef u32    u32x4  __attribute__((ext_vector_type(4)));
typedef u32    u32x2  __attribute__((ext_vector_type(2)));

#define EPSF 1e-5f
#define NH 8
#define NTP 416                        // 400 text tokens padded to 416 (13*32)
#define LOG2E 1.4426950408889634f
#define QSCALE (0.125f * LOG2E)

static __device__ __forceinline__ u16 f2bf(float f){
  u32 u = __builtin_bit_cast(u32, f);
  u += 0x7FFFu + ((u >> 16) & 1u);     // RNE (finite inputs only)
  return (u16)(u >> 16);
}
static __device__ __forceinline__ float u2f(u32 u){
  return __builtin_bit_cast(float, u);
}
static __device__ __forceinline__ u32 pk2bf(float lo, float hi){
  float2 f; f.x = lo; f.y = hi;
  __hip_bfloat162 b = __float22bfloat162_rn(f);
  u32 l = (u32)__bfloat16_as_ushort(b.x);
  u32 h = (u32)__bfloat16_as_ushort(b.y);
  return l | (h << 16);
}
static __device__ __forceinline__ f32x4 mfma16(short8 a, short8 b, f32x4 c){
  return __builtin_amdgcn_mfma_f32_16x16x32_bf16(a, b, c, 0, 0, 0);
}
static __device__ __forceinline__ void gld16(const void* g, void* l){
  __builtin_amdgcn_global_load_lds(
      (const __attribute__((address_space(1))) u32*)g,
      (__attribute__((address_space(3))) u32*)l, 16, 0, 0);
}

// ---------------------------------------------------------------------------
// Weight convert: wT[c][r] = bf16(w[r][c] * gamma[c]*rsqrt(var[c]+eps))
// ---------------------------------------------------------------------------
__global__ __launch_bounds__(256) void wconv_kernel(
    const float* __restrict__ w, const float* __restrict__ gamma,
    const float* __restrict__ var, u16* __restrict__ wT, int R, int C)
{
  __shared__ u16 tile[64*65];
  const int tx = blockIdx.x, ty = blockIdx.y, tid = threadIdx.x;
  #pragma unroll
  for (int i = 0; i < 16; ++i){
    int lin = tid + i*256;
    int rr = lin >> 6, cc = lin & 63;
    int c = tx*64 + cc;
    float s = gamma[c] * rsqrtf(var[c] + EPSF);
    tile[rr*65 + cc] = f2bf(w[(size_t)(ty*64 + rr)*C + c] * s);
  }
  __syncthreads();
  #pragma unroll
  for (int i = 0; i < 16; ++i){
    int lin = tid + i*256;
    int cc = lin >> 6, rr = lin & 63;
    wT[(size_t)(tx*64 + cc)*R + ty*64 + rr] = tile[rr*65 + cc];
  }
}

// text -> bf16, padded to 512 rows (rows >=400 zero)
__global__ __launch_bounds__(256) void textconv_kernel(
    const float* __restrict__ text, u16* __restrict__ tbf)
{
  int idx = blockIdx.x*256 + threadIdx.x;   // 512*512
  int r = idx >> 9, c = idx & 511;
  float v = (r < 400) ? text[r*512 + c] : 0.f;
  tbf[idx] = f2bf(v);
}

// bias table, fragment-tiled (x log2e); t>=400 -> -1e30
__global__ __launch_bounds__(256) void bias_kernel(
    const float* __restrict__ ab, u16* __restrict__ btab)
{
  int idx = blockIdx.x*256 + threadIdx.x;   // 8*1024*416
  int t = idx % 416;
  int n = (idx / 416) & 1023;
  int h = idx / (416*1024);
  float v;
  if (t >= 400) v = -1e30f;
  else {
    int i = n >> 5, j = n & 31;
    int a = t / 100, bb = t % 100;
    v = ab[h*10000 + abs(i - a)*100 + abs(j - bb)] * LOG2E;
  }
  size_t o = ((size_t)(h*16 + (n >> 6))*13 + (t >> 5))*2048
           + ((n >> 4) & 3)*512 + ((t >> 4) & 1)*256
           + ((t >> 2) & 3)*64 + (n & 15)*4 + (t & 3);
  btab[o] = f2bf(v);
}

// ---------------------------------------------------------------------------
// 128x128 tile GEMM (m97 structure). BT is [N][K] bf16 (BN scale folded).
// NXB>0: flat-grid XCD-chunked decode (xcd=L&7, cb=s%NXB, rb=xcd*rbpx+s/NXB)
// MODE 0: A=x fp32 (reg-stage cvt) -> q_ws[b][h][n][64] bf16, *QSCALE folded
// MODE 1: A=text_bf -> K/V fragment-tiled (t<416 guard)
// MODE 2: A=a_ws bf16 -> d_out fp32 (+BN shift), rows offset row_base
// ---------------------------------------------------------------------------
template<int MODE, int NXB>
__global__ __launch_bounds__(256) void gemm_kernel(
    const void* __restrict__ Ap, const u16* __restrict__ BT,
    const float* __restrict__ g1, const float* __restrict__ b1,
    const float* __restrict__ m1, const float* __restrict__ v1,
    void* __restrict__ o0, void* __restrict__ o1, int K, int row_base,
    int rbpx)
{
  __shared__ u16 lds[8192];                 // A [0,4096), B [4096,8192)
  const int tid = threadIdx.x;
  int cb, rb;
  if (NXB > 0){
    const int L = blockIdx.x;
    const int xcd = L & 7, s = L >> 3;
    cb = s % NXB;
    rb = xcd * rbpx + s / NXB;
  } else {
    cb = blockIdx.x; rb = blockIdx.y;
  }
  const int lane = tid & 63, wid = tid >> 6;
  const int lg = lane >> 4, lc = lane & 15;
  const int wr = wid >> 1, wc = wid & 1;
  const int row0 = rb*128, col0 = cb*128;
  f32x4 acc[4][4] = {};
  const int nkb = K >> 5;

  for (int kb = 0; kb < nkb; ++kb){
    if (MODE == 0){
      const float* A = (const float*)Ap;
      #pragma unroll
      for (int it = 0; it < 4; ++it){
        int lin = tid + it*256;
        int row = lin >> 3, c4 = lin & 7;
        const fl4 v = *(const fl4*)(A + (size_t)(row0 + row)*K + kb*32 + c4*4);
        u32x2 p;
        p[0] = (u32)f2bf(v[0]) | ((u32)f2bf(v[1]) << 16);
        p[1] = (u32)f2bf(v[2]) | ((u32)f2bf(v[3]) << 16);
        *(u32x2*)&lds[row*32 + c4*4] = p;
      }
    } else {
      const u16* A = (const u16*)Ap;
      #pragma unroll
      for (int it = 0; it < 2; ++it){
        int lin = tid + it*256;
        int row = lin >> 2, seg = lin & 3;
        gld16(A + (size_t)(row0 + row)*K + kb*32 + seg*8, &lds[lin*8]);
      }
    }
    #pragma unroll
    for (int it = 0; it < 2; ++it){
      int lin = tid + it*256;
      int col = lin >> 2, seg = lin & 3;
      gld16(BT + (size_t)(col0 + col)*K + kb*32 + seg*8, &lds[4096 + lin*8]);
    }
    __syncthreads();
    short8 af[4], bfr[4];
    #pragma unroll
    for (int rt = 0; rt < 4; ++rt)
      af[rt] = *(const short8*)&lds[(wr*64 + rt*16 + lc)*32 + lg*8];
    #pragma unroll
    for (int ct = 0; ct < 4; ++ct)
      bfr[ct] = *(const short8*)&lds[4096 + (wc*64 + ct*16 + lc)*32 + lg*8];
    #pragma unroll
    for (int rt = 0; rt < 4; ++rt)
      #pragma unroll
      for (int ct = 0; ct < 4; ++ct)
        acc[rt][ct] = mfma16(af[rt], bfr[ct], acc[rt][ct]);
    __syncthreads();
  }

  if (MODE == 0){
    u16* qws = (u16*)o0;
    #pragma unroll
    for (int ct = 0; ct < 4; ++ct){
      int c = col0 + wc*64 + ct*16 + lc;
      float sc = g1[c] * rsqrtf(v1[c] + EPSF);
      float sh = (b1[c] - m1[c]*sc) * QSCALE;   // 0.125*log2e fold
      int h = c >> 6, dk = c & 63;
      #pragma unroll
      for (int rt = 0; rt < 4; ++rt)
        #pragma unroll
        for (int r = 0; r < 4; ++r){
          int mr = row0 + wr*64 + rt*16 + lg*4 + r;
          int b = mr >> 10, n = mr & 1023;
          qws[(size_t)((b*NH + h)*1024 + n)*64 + dk] =
              f2bf(acc[rt][ct][r]*QSCALE + sh);
        }
    }
  } else if (MODE == 1){
    u16* Kw = (u16*)o0; u16* Vw = (u16*)o1;
    #pragma unroll
    for (int ct = 0; ct < 4; ++ct){
      int c = col0 + wc*64 + ct*16 + lc;
      float sc = g1[c] * rsqrtf(v1[c] + EPSF);
      float sh = b1[c] - m1[c]*sc;
      int h = c / 320, sub = c % 320;
      #pragma unroll
      for (int rt = 0; rt < 4; ++rt)
        #pragma unroll
        for (int r = 0; r < 4; ++r){
          int t = row0 + wr*64 + rt*16 + lg*4 + r;
          if (t < NTP){
            u16 val = f2bf(acc[rt][ct][r] + sh);
            if (sub < 64){
              // K fragment-tiled
              size_t o = ((size_t)h*13 + (t >> 5))*2048
                       + ((t >> 4) & 1)*1024 + (sub >> 5)*512
                       + ((sub >> 3) & 3)*128 + (t & 15)*8 + (sub & 7);
              Kw[o] = val;
            } else {
              int dv = sub - 64;
              // V fragment-tiled
              size_t o = ((size_t)h*13 + (t >> 5))*8192
                       + (dv >> 6)*2048 + ((dv >> 4) & 3)*512
                       + ((t >> 3) & 3)*128 + (dv & 15)*8 + (t & 7);
              Vw[o] = val;
            }
          }
        }
    }
  } else {
    float* outp = (float*)o0;
    #pragma unroll
    for (int ct = 0; ct < 4; ++ct){
      int c = col0 + wc*64 + ct*16 + lc;
      float sc = g1[c] * rsqrtf(v1[c] + EPSF);
      float sh = b1[c] - m1[c]*sc;
      #pragma unroll
      for (int rt = 0; rt < 4; ++rt)
        #pragma unroll
        for (int r = 0; r < 4; ++r){
          int mr = row_base + row0 + wr*64 + rt*16 + lg*4 + r;
          outp[(size_t)mr*512 + c] = acc[rt][ct][r] + sh;
        }
    }
  }
}

// ---------------------------------------------------------------------------
// Flash attention, swapped QK^T, fragment-tiled coalesced loads, reg-pipelined
// K/bias prefetch, XCD-aware flat-grid decode (h = L&7, same-(qt,h) blocks
// slot-consecutive -> K/V/btab head slices L2-resident).
// Block = 64 q x (h, b); 4 waves. Chunk = 32 t, 13 chunks, full unroll.
// P double-buffered in LDS (2 x 5120 B), 1 barrier per chunk.
// ---------------------------------------------------------------------------
__global__ __launch_bounds__(256, 3) void attn_kernel(
    const u16* __restrict__ qws, const u16* __restrict__ Kw,
    const u16* __restrict__ Vw, const u16* __restrict__ btab,
    u16* __restrict__ aws, int b_base, int bzbits)
{
  __shared__ char Pb[2][64*80];     // P bf16 [64 q][32 t], row stride 80 B
  __shared__ float lsum[64];

  const int tid = threadIdx.x;
  const int lane = tid & 63, wid = tid >> 6;
  const int lg = lane >> 4, lc = lane & 15;

  // XCD-aware decode: L = slot*8 + xcd (HW round-robins xcd = L&7)
  const int L = blockIdx.x;
  const int slot = L >> 3;
  const int bz = slot & ((1 << bzbits) - 1);
  const int qt = slot >> bzbits;            // 0..15
  const int h = L & 7;                      // one head per XCD
  const int b = b_base + bz, n0 = qt*64;

  // Q B-frags (col=q=lc within wave's 16 rows), QSCALE folded at q-proj
  const u16* qp = qws + ((size_t)((b*NH + h)*1024 + n0 + wid*16 + lc))*64 + lg*8;
  const short8 qf0 = *(const short8*)qp;
  const short8 qf1 = *(const short8*)(qp + 32);

  // fragment-tiled bases (u16 units) — fully coalesced per-wave reads
  const u16* kbase = Kw + (size_t)h*13*2048 + lg*128 + lc*8;
  const u16* vbase = Vw + (size_t)h*13*8192 + wid*2048 + lg*128 + lc*8;
  const u16* btb   = btab + ((size_t)(h*16 + qt)*13)*2048 + wid*512 + lg*64 + lc*4;

  float lpart = 0.f;
  f32x4 acc[4][4] = {};
  char* pwr = &Pb[0][0] + (wid*16 + lc)*80 + lg*8;   // + buf*5120 + tt*32

  // prefetch slots (static indices via full unroll)
  short8 kfs[2][4];                 // [slot][tt*2 + kh]
  u32x2  bws[2][2];                 // [slot][tt]

  // prologue: issue K/bias for chunk 0 into slot 0
  kfs[0][0] = *(const short8*)(kbase);
  kfs[0][1] = *(const short8*)(kbase + 512);
  kfs[0][2] = *(const short8*)(kbase + 1024);
  kfs[0][3] = *(const short8*)(kbase + 1536);
  bws[0][0] = *(const u32x2*)(btb);
  bws[0][1] = *(const u32x2*)(btb + 256);

  #pragma unroll
  for (int c = 0; c < 13; ++c){
    const int s = c & 1, ns = (c + 1) & 1;
    // ---- issue V(c) loads (consumed after barrier)
    const u16* vc = vbase + (size_t)c*8192;
    short8 vf0 = *(const short8*)(vc);
    short8 vf1 = *(const short8*)(vc + 512);
    short8 vf2 = *(const short8*)(vc + 1024);
    short8 vf3 = *(const short8*)(vc + 1536);
    // ---- QK(c) with prefetched K/bias; write P into Pb[s]
    #pragma unroll
    for (int tt = 0; tt < 2; ++tt){
      u32x2 bw = bws[s][tt];
      f32x4 sv;
      sv[0] = u2f(bw[0] << 16); sv[1] = u2f(bw[0] & 0xffff0000u);
      sv[2] = u2f(bw[1] << 16); sv[3] = u2f(bw[1] & 0xffff0000u);
      sv = mfma16(kfs[s][tt*2 + 0], qf0, sv);
      sv = mfma16(kfs[s][tt*2 + 1], qf1, sv);
      float p0 = __builtin_exp2f(sv[0]);
      float p1 = __builtin_exp2f(sv[1]);
      float p2 = __builtin_exp2f(sv[2]);
      float p3 = __builtin_exp2f(sv[3]);
      lpart += (p0 + p1) + (p2 + p3);
      u32x2 pw;
      pw[0] = pk2bf(p0, p1);
      pw[1] = pk2bf(p2, p3);
      *(u32x2*)(pwr + s*5120 + tt*32) = pw;
    }
    // ---- issue K/bias(c+1) into slot ns (consumed next iteration)
    if (c < 12){
      const u16* kc = kbase + (size_t)(c + 1)*2048;
      kfs[ns][0] = *(const short8*)(kc);
      kfs[ns][1] = *(const short8*)(kc + 512);
      kfs[ns][2] = *(const short8*)(kc + 1024);
      kfs[ns][3] = *(const short8*)(kc + 1536);
      const u16* bc = btb + (size_t)(c + 1)*2048;
      bws[ns][0] = *(const u32x2*)(bc);
      bws[ns][1] = *(const u32x2*)(bc + 256);
    }
    __syncthreads();                                  // Pb[s] ready for all
    // ---- PV(c): all 64 q x this wave's 64 dv
    const char* pb = &Pb[s][0];
    short8 pa[4];
    #pragma unroll
    for (int rt = 0; rt < 4; ++rt)
      pa[rt] = *(const short8*)(pb + (rt*16 + lc)*80 + lg*16);
    __builtin_amdgcn_s_setprio(1);
    #pragma unroll
    for (int rt = 0; rt < 4; ++rt){
      acc[rt][0] = mfma16(pa[rt], vf0, acc[rt][0]);
      acc[rt][1] = mfma16(pa[rt], vf1, acc[rt][1]);
      acc[rt][2] = mfma16(pa[rt], vf2, acc[rt][2]);
      acc[rt][3] = mfma16(pa[rt], vf3, acc[rt][3]);
    }
    __builtin_amdgcn_s_setprio(0);
  }

  // ---- row sums -> LDS
  lpart += __shfl_xor(lpart, 16);
  lpart += __shfl_xor(lpart, 32);
  if (lane < 16) lsum[wid*16 + lane] = lpart;
  __syncthreads();

  // ---- epilogue: /l (rcp), exact GELU (A&S erf, rcp), write aws bf16
  #pragma unroll
  for (int rt = 0; rt < 4; ++rt){
    #pragma unroll
    for (int r = 0; r < 4; ++r){
      const int qrow = rt*16 + lg*4 + r;
      const float linv = __builtin_amdgcn_rcpf(lsum[qrow]);
      const size_t obase = ((size_t)(bz*1024 + n0 + qrow))*2048 + h*256;
      #pragma unroll
      for (int ct = 0; ct < 4; ++ct){
        float x = acc[rt][ct][r] * linv;
        float u = x * 0.70710678f;
        float au = fabsf(u);
        float t = __builtin_amdgcn_rcpf(__builtin_fmaf(0.3275911f, au, 1.0f));
        float poly = t*(0.254829592f + t*(-0.284496736f + t*(1.421413741f +
                     t*(-1.453152027f + t*1.061405429f))));
        float erfv = 1.0f - poly*__expf(-u*u);
        erfv = (u < 0.f) ? -erfv : erfv;
        float g = 0.5f * x * (1.0f + erfv);
        aws[obase + wid*64 + ct*16 + lc] = f2bf(g);
      }
    }
  }
}

// ---------------------------------------------------------------------------
extern "C" void kernel_launch(void* const* d_in, const int* in_sizes, int n_in,
                              void* d_out, int out_size, void* d_ws, size_t ws_size,
                              hipStream_t stream)
{
  (void)in_sizes; (void)n_in; (void)out_size;
  const float* x    = (const float*)d_in[0];
  const float* text = (const float*)d_in[1];
  const float* q_w  = (const float*)d_in[2];
  const float* q_g  = (const float*)d_in[3];
  const float* q_b  = (const float*)d_in[4];
  const float* q_m  = (const float*)d_in[5];
  const float* q_v  = (const float*)d_in[6];
  const float* kv_w = (const float*)d_in[7];
  const float* kv_g = (const float*)d_in[8];
  const float* kv_b = (const float*)d_in[9];
  const float* kv_m = (const float*)d_in[10];
  const float* kv_v = (const float*)d_in[11];
  const float* p_w  = (const float*)d_in[12];
  const float* p_g  = (const float*)d_in[13];
  const float* p_b  = (const float*)d_in[14];
  const float* p_m  = (const float*)d_in[15];
  const float* p_v  = (const float*)d_in[16];
  const float* ab   = (const float*)d_in[17];
  float* out = (float*)d_out;

  char* ws = (char*)d_ws;
  u16* qwT   = (u16*)(ws + 0);            //  512x512   [N][K]
  u16* kvwT  = (u16*)(ws + 524288);       // 2560x512   [N][K]
  u16* pwT   = (u16*)(ws + 3145728);      //  512x2048  [N][K]
  u16* textb = (u16*)(ws + 5242880);      //  512x512
  u16* btab  = (u16*)(ws + 5767168);      //  8x16x13x2048 (frag-tiled, x log2e)
  u16* Kw    = (u16*)(ws + 12582912);     //  8x13x2048 (frag-tiled)
  u16* Vw    = (u16*)(ws + 13008896);     //  8x13x8192 (frag-tiled)
  u16* qws   = (u16*)(ws + 14712832);     //  32x8x1024x64
  u16* aws   = (u16*)(ws + 48267264);     //  32768x2048 (full) or 8192x2048

  const bool full = ws_size >= (size_t)182484992ull;

  wconv_kernel<<<dim3(8, 8),  256, 0, stream>>>(q_w,  q_g,  q_v,  qwT,  512,  512);
  wconv_kernel<<<dim3(40, 8), 256, 0, stream>>>(kv_w, kv_g, kv_v, kvwT, 512,  2560);
  wconv_kernel<<<dim3(8, 32), 256, 0, stream>>>(p_w,  p_g,  p_v,  pwT,  2048, 512);
  textconv_kernel<<<1024, 256, 0, stream>>>(text, textb);
  bias_kernel<<<13312, 256, 0, stream>>>(ab, btab);

  // kv-proj: M=512(pad) N=2560 K=512 (small; 2D grid)
  gemm_kernel<1, 0><<<dim3(20, 4), 256, 0, stream>>>(
      textb, kvwT, kv_g, kv_b, kv_m, kv_v, Kw, Vw, 512, 0, 0);
  // q-proj: M=32768 N=512 K=512, flat 1024, XCD-chunked (rbpx=32)
  gemm_kernel<0, 4><<<1024, 256, 0, stream>>>(
      x, qwT, q_g, q_b, q_m, q_v, qws, nullptr, 512, 0, 32);

  if (full){
    // flat 4096 blocks: h=L&7, slot=L>>3: bz=slot&31, qt=slot>>5
    attn_kernel<<<4096, 256, 0, stream>>>(qws, Kw, Vw, btab, aws, 0, 5);
    // proj: M=32768 N=512 K=2048, flat 1024, XCD-chunked (rbpx=32)
    gemm_kernel<2, 4><<<1024, 256, 0, stream>>>(
        aws, pwT, p_g, p_b, p_m, p_v, out, nullptr, 2048, 0, 32);
  } else {
    for (int q = 0; q < 4; ++q){
      attn_kernel<<<1024, 256, 0, stream>>>(qws, Kw, Vw, btab, aws, q*8, 3);
      gemm_kernel<2, 4><<<256, 256, 0, stream>>>(
          aws, pwT, p_g, p_b, p_m, p_v, out, nullptr, 2048, q*8192, 8);
    }
  }
}